// Round 14
// baseline (74.696 us; speedup 1.0000x reference)
//
#include <hip/hip_runtime.h>
#include <hip/hip_bf16.h>

#define Bn 8
#define Sn 2048
#define Dn 512
#define Kn 64

typedef _Float16 half8 __attribute__((ext_vector_type(8)));
typedef _Float16 half4v __attribute__((ext_vector_type(4)));
typedef __fp16 fp16x2 __attribute__((ext_vector_type(2)));
typedef float f32x4 __attribute__((ext_vector_type(4)));

#define MFMA16(a,b,c) __builtin_amdgcn_mfma_f32_16x16x32_f16(a,b,c,0,0,0)
#define LOG2E 1.4426950408889634f
#define EXP2(x) __builtin_amdgcn_exp2f(x)

// LDS tiles [rows][64] f16 (128B rows), XOR-swizzled on 16B granules.
__device__ __forceinline__ half8 ldfrag(const _Float16* base, int row, int k8){
    const int scol = k8 ^ (row & 7);
    return *(const half8*)((const char*)base + row*128 + scol*16);
}

// Fragment layouts in global memory (16B granules, lane = l4*16+l15):
//  Qh2/Kh2: granule (t*2+ks)*64+lane = M[t*16+l15][ks*32+l4*8 .. +8]   (t = global 16-row tile)
//  Vt2:     granule (((b*32+sc)*2+ks)*32+dt)*64+lane = V[dt*16+l15][sc*64+(ks*4+l4)*8 .. +8]
// Q pre-scaled by log2(e). Stats: z[s] = sum_q 2^(l2-64); CS[s] = -(64+log2 z).
// attn: P[q,s] = 2^(l2[q,s] + CS[s]) via MFMA C-init; exp = raw v_exp_f32.

// ---- Kernel 0: W transpose+cast ----
__global__ __launch_bounds__(256) void wtrans_kernel(
    const float* __restrict__ Wk, const float* __restrict__ Wq,
    _Float16* __restrict__ Wt16)
{
    const int n = blockIdx.x;
    const int t = threadIdx.x;
    const float* src = (n < 64) ? Wq : Wk;
    const int nn = n & 63;
    #pragma unroll
    for (int i = 0; i < 2; ++i){
        const int k = t + 256*i;
        Wt16[(size_t)n*Dn + k] = (_Float16)src[(size_t)k*Kn + nn];
    }
}

// ---- Kernel 1: fused Q/K projection + V transpose (32 rows per block) ----
__global__ __launch_bounds__(256, 2) void prep_kernel(
    const float* __restrict__ X, const _Float16* __restrict__ Wt16,
    const float* __restrict__ bk, const float* __restrict__ bq,
    _Float16* __restrict__ Qh2, _Float16* __restrict__ Kh2,
    _Float16* __restrict__ Vt2)
{
    __shared__ _Float16 Xt[2][32*64];
    const int bid = blockIdx.x;
    const int b = bid & 7, sb32 = bid >> 3;
    const int tid = threadIdx.x, lane = tid & 63, w = tid >> 6;
    const int l15 = lane & 15, l4 = lane >> 4;

    const int srow = tid >> 3, sg = tid & 7;
    const float* Xs = X + ((size_t)(b*Sn + sb32*32) + srow)*Dn + sg*8;
    const int sdst = srow*128 + (((sg ^ (srow & 7) ^ (srow >> 3)) & 7) * 16);

    const int n0 = w*32 + l15;
    const _Float16* Wp0 = Wt16 + (size_t)n0*Dn + l4*8;
    const _Float16* Wp1 = Wp0 + (size_t)16*Dn;

    f32x4 acc[2][2];
    #pragma unroll
    for (int i = 0; i < 2; ++i)
        #pragma unroll
        for (int j = 0; j < 2; ++j){ f32x4 z = {0.f,0.f,0.f,0.f}; acc[i][j] = z; }

    {
        const float4 v0 = *(const float4*)(Xs);
        const float4 v1 = *(const float4*)(Xs + 4);
        half8 h;
        h[0]=(_Float16)v0.x; h[1]=(_Float16)v0.y; h[2]=(_Float16)v0.z; h[3]=(_Float16)v0.w;
        h[4]=(_Float16)v1.x; h[5]=(_Float16)v1.y; h[6]=(_Float16)v1.z; h[7]=(_Float16)v1.w;
        *(half8*)((char*)Xt[0] + sdst) = h;
    }
    __syncthreads();

    const int dcol = w*16 + l15;
    #pragma unroll
    for (int kc = 0; kc < 8; ++kc){
        const _Float16* XtC = Xt[kc & 1];
        float4 nv0, nv1;
        if (kc < 7){
            nv0 = *(const float4*)(Xs + (kc+1)*64);
            nv1 = *(const float4*)(Xs + (kc+1)*64 + 4);
        }
        const half8 wf00 = *(const half8*)(Wp0 + kc*64);
        const half8 wf01 = *(const half8*)(Wp0 + kc*64 + 32);
        const half8 wf10 = *(const half8*)(Wp1 + kc*64);
        const half8 wf11 = *(const half8*)(Wp1 + kc*64 + 32);
        #pragma unroll
        for (int ks = 0; ks < 2; ++ks){
            #pragma unroll
            for (int qt = 0; qt < 2; ++qt){
                const int rw = qt*16 + l15;
                const int g = ((ks*4 + l4) ^ (rw & 7) ^ (rw >> 3)) & 7;
                const half8 a = *(const half8*)((const char*)XtC + rw*128 + g*16);
                acc[qt][0] = MFMA16(a, ks ? wf01 : wf00, acc[qt][0]);
                acc[qt][1] = MFMA16(a, ks ? wf11 : wf10, acc[qt][1]);
            }
        }
        {
            half8 hv;
            #pragma unroll
            for (int e = 0; e < 8; ++e){
                const int rw = l4*8 + e;
                const int g = ((dcol >> 3) ^ e ^ l4) & 7;
                hv[e] = XtC[rw*64 + g*8 + (dcol & 7)];
            }
            const size_t G = (((size_t)(b*32 + (sb32 >> 1))*2 + (sb32 & 1))*32 + kc*4 + w)*64 + lane;
            *(half8*)(Vt2 + G*8) = hv;
        }
        if (kc < 7){
            half8 h;
            h[0]=(_Float16)nv0.x; h[1]=(_Float16)nv0.y; h[2]=(_Float16)nv0.z; h[3]=(_Float16)nv0.w;
            h[4]=(_Float16)nv1.x; h[5]=(_Float16)nv1.y; h[6]=(_Float16)nv1.z; h[7]=(_Float16)nv1.w;
            *(half8*)((char*)Xt[(kc+1) & 1] + sdst) = h;
        }
        __syncthreads();
    }

    _Float16* tile16 = &Xt[0][0];
    #pragma unroll
    for (int qt = 0; qt < 2; ++qt){
        const int ql = qt*16 + l4*4;
        #pragma unroll
        for (int nt = 0; nt < 2; ++nt){
            const int n = w*32 + nt*16 + l15;
            const bool isQ = (n < 64);
            const float bias = isQ ? bq[n] : bk[n - 64];
            const float scale = isQ ? LOG2E : 1.0f;
            #pragma unroll
            for (int r = 0; r < 4; ++r)
                tile16[(ql + r)*128 + n] = (_Float16)((acc[qt][nt][r] + bias) * scale);
        }
    }
    __syncthreads();
    #pragma unroll
    for (int i = 0; i < 2; ++i){
        const int g = tid + 256*i;
        const int isK = g >> 8, qtl = (g >> 7) & 1, ks = (g >> 6) & 1, ln = g & 63;
        const int l4g = ln >> 4, l15g = ln & 15;
        const half8 h = *(const half8*)&tile16[(qtl*16 + l15g)*128 + isK*64 + ks*32 + l4g*8];
        const size_t tg = (size_t)b*128 + sb32*2 + qtl;
        _Float16* dst = (isK ? Kh2 : Qh2) + ((tg*2 + ks)*64 + ln)*8;
        *(half8*)dst = h;
    }
}

// ---- Kernel 2: per-(b,s) column denominators (base-2, fixed M0=64) ----
#define SBODY(QC0,QC1,QC2,QC3, QN0,QN1,QN2,QN3) do { \
    QN0 = *(const half8*)(Qp); \
    QN1 = *(const half8*)(Qp + 1024); \
    QN2 = *(const half8*)(Qp + 2048); \
    QN3 = *(const half8*)(Qp + 3072); \
    Qp += 8192; \
    f32x4 c0 = cinit, c1 = cinit; \
    c0 = MFMA16(ka0, QC0, c0); c0 = MFMA16(ka1, QC1, c0); \
    c1 = MFMA16(ka0, QC2, c1); c1 = MFMA16(ka1, QC3, c1); \
    _Pragma("unroll") \
    for (int r = 0; r < 4; ++r) \
        z[r] += EXP2(c0[r]) + EXP2(c1[r]); \
} while(0)

__global__ __launch_bounds__(512, 2) void stats_kernel(
    const _Float16* __restrict__ Qh2, const _Float16* __restrict__ Kh2,
    float* __restrict__ CS)
{
    __shared__ float zred[2][64];
    const int bid = blockIdx.x;
    const int b = bid & 7, stb = bid >> 3;
    const int tid = threadIdx.x, lane = tid & 63, w = tid >> 6;
    const int l15 = lane & 15, l4 = lane >> 4;
    const int sw = w & 3, qh = w >> 2, qh2 = qh*2;

    const half8 ka0 = *(const half8*)(Kh2 + ((size_t)((b*128 + stb*4 + sw)*2 + 0)*64 + lane)*8);
    const half8 ka1 = *(const half8*)(Kh2 + ((size_t)((b*128 + stb*4 + sw)*2 + 1)*64 + lane)*8);

    const char* Qp = (const char*)Qh2 + (size_t)(b*128 + qh2)*2048 + lane*16;

    const f32x4 cinit = {-64.f, -64.f, -64.f, -64.f};
    float z[4] = {0.f, 0.f, 0.f, 0.f};

    half8 qbA0, qbA1, qbA2, qbA3, qbB0, qbB1, qbB2, qbB3;
    qbA0 = *(const half8*)(Qp);
    qbA1 = *(const half8*)(Qp + 1024);
    qbA2 = *(const half8*)(Qp + 2048);
    qbA3 = *(const half8*)(Qp + 3072);
    Qp += 8192;

    for (int qc = 0; qc < 32; qc += 2){
        SBODY(qbA0,qbA1,qbA2,qbA3, qbB0,qbB1,qbB2,qbB3);
        SBODY(qbB0,qbB1,qbB2,qbB3, qbA0,qbA1,qbA2,qbA3);
    }
    #pragma unroll
    for (int d = 1; d < 16; d <<= 1)
        #pragma unroll
        for (int r = 0; r < 4; ++r)
            z[r] += __shfl_xor(z[r], d);
    if (l15 == 0){
        const int sl = sw*16 + l4*4;
        #pragma unroll
        for (int r = 0; r < 4; ++r) zred[qh][sl+r] = z[r];
    }
    __syncthreads();
    if (tid < 64)
        CS[b*Sn + stb*64 + tid] = -(64.0f + __log2f(zred[0][tid] + zred[1][tid]));
}

// ---- Kernel 3: attn, 64q x 256d, 4 waves, 2 blocks/CU, 2-sc supersteps ----
// P tile: [64 q][128 s], 256B rows, granule-XOR swizzle on low 3 bits.
#define WRP(PT, QT, C, PWO) do { \
    const float e0 = EXP2(C[0]); \
    const float e1 = EXP2(C[1]); \
    const float e2 = EXP2(C[2]); \
    const float e3 = EXP2(C[3]); \
    const fp16x2 plo = __builtin_amdgcn_cvt_pkrtz(e0, e1); \
    const fp16x2 phi = __builtin_amdgcn_cvt_pkrtz(e2, e3); \
    uint2 pu; \
    pu.x = __builtin_bit_cast(unsigned int, plo); \
    pu.y = __builtin_bit_cast(unsigned int, phi); \
    *(uint2*)((char*)(PT) + (QT)*4096 + (PWO)) = pu; \
} while(0)

#define SSTEP(PT, KA, KAN, CSA0, CSA1, CSN0, CSN1, VC, VN) do { \
    __builtin_amdgcn_s_setprio(1); \
    f32x4 c0 = {CSA0.x, CSA0.y, CSA0.z, CSA0.w}; \
    f32x4 c1 = c0, c2 = c0, c3 = c0; \
    c0 = MFMA16(KA[0], qb[0][0], c0); c0 = MFMA16(KA[1], qb[0][1], c0); \
    c1 = MFMA16(KA[0], qb[1][0], c1); c1 = MFMA16(KA[1], qb[1][1], c1); \
    c2 = MFMA16(KA[0], qb[2][0], c2); c2 = MFMA16(KA[1], qb[2][1], c2); \
    c3 = MFMA16(KA[0], qb[3][0], c3); c3 = MFMA16(KA[1], qb[3][1], c3); \
    f32x4 d0 = {CSA1.x, CSA1.y, CSA1.z, CSA1.w}; \
    f32x4 d1 = d0, d2 = d0, d3 = d0; \
    d0 = MFMA16(KA[2], qb[0][0], d0); d0 = MFMA16(KA[3], qb[0][1], d0); \
    d1 = MFMA16(KA[2], qb[1][0], d1); d1 = MFMA16(KA[3], qb[1][1], d1); \
    d2 = MFMA16(KA[2], qb[2][0], d2); d2 = MFMA16(KA[3], qb[2][1], d2); \
    d3 = MFMA16(KA[2], qb[3][0], d3); d3 = MFMA16(KA[3], qb[3][1], d3); \
    __builtin_amdgcn_s_setprio(0); \
    KAN[0] = *(const half8*)(Kp); \
    KAN[1] = *(const half8*)(Kp + 1024); \
    KAN[2] = *(const half8*)(Kp + 8192); \
    KAN[3] = *(const half8*)(Kp + 8192 + 1024); \
    Kp += 16384; \
    CSN0 = *(const float4*)Cp; \
    CSN1 = *(const float4*)(Cp + 64); \
    Cp += 128; \
    WRP(PT, 0, c0, pw0); WRP(PT, 1, c1, pw0); \
    WRP(PT, 2, c2, pw0); WRP(PT, 3, c3, pw0); \
    WRP(PT, 0, d0, pw1); WRP(PT, 1, d1, pw1); \
    WRP(PT, 2, d2, pw1); WRP(PT, 3, d3, pw1); \
    asm volatile("s_waitcnt lgkmcnt(0)\n\ts_barrier" ::: "memory"); \
    half8 vm[8]; \
    _Pragma("unroll") \
    for (int d_ = 0; d_ < 4; ++d_){ \
        vm[d_]   = *(const half8*)(Vp0 + d_*1024); \
        vm[4+d_] = *(const half8*)(Vp1 + d_*1024); \
    } \
    Vp0 += 65536; Vp1 += 65536; \
    __builtin_amdgcn_s_setprio(1); \
    { const char* PB = (const char*)(PT); \
      _Pragma("unroll") \
      for (int ks = 0; ks < 2; ++ks){ \
        const int po = pa[ks]; \
        const half8 pa0 = *(const half8*)(PB + 0*4096 + po); \
        const half8 pa1 = *(const half8*)(PB + 1*4096 + po); \
        const half8 pa2 = *(const half8*)(PB + 2*4096 + po); \
        const half8 pa3 = *(const half8*)(PB + 3*4096 + po); \
        _Pragma("unroll") \
        for (int d_ = 0; d_ < 4; ++d_){ \
            acc[0][d_] = MFMA16(pa0, VC[ks*4+d_], acc[0][d_]); \
            acc[1][d_] = MFMA16(pa1, VC[ks*4+d_], acc[1][d_]); \
            acc[2][d_] = MFMA16(pa2, VC[ks*4+d_], acc[2][d_]); \
            acc[3][d_] = MFMA16(pa3, VC[ks*4+d_], acc[3][d_]); \
        } \
      } } \
    __builtin_amdgcn_s_setprio(0); \
    _Pragma("unroll") \
    for (int d_ = 0; d_ < 4; ++d_){ \
        VN[d_]   = *(const half8*)(Vp0 + d_*1024); \
        VN[4+d_] = *(const half8*)(Vp1 + d_*1024); \
    } \
    Vp0 += 65536; Vp1 += 65536; \
    __builtin_amdgcn_s_setprio(1); \
    { const char* PB = (const char*)(PT); \
      _Pragma("unroll") \
      for (int ks = 0; ks < 2; ++ks){ \
        const int po = pa[2+ks]; \
        const half8 pa0 = *(const half8*)(PB + 0*4096 + po); \
        const half8 pa1 = *(const half8*)(PB + 1*4096 + po); \
        const half8 pa2 = *(const half8*)(PB + 2*4096 + po); \
        const half8 pa3 = *(const half8*)(PB + 3*4096 + po); \
        _Pragma("unroll") \
        for (int d_ = 0; d_ < 4; ++d_){ \
            acc[0][d_] = MFMA16(pa0, vm[ks*4+d_], acc[0][d_]); \
            acc[1][d_] = MFMA16(pa1, vm[ks*4+d_], acc[1][d_]); \
            acc[2][d_] = MFMA16(pa2, vm[ks*4+d_], acc[2][d_]); \
            acc[3][d_] = MFMA16(pa3, vm[ks*4+d_], acc[3][d_]); \
        } \
      } } \
    __builtin_amdgcn_s_setprio(0); \
} while(0)

__global__ __launch_bounds__(256, 2) void attn_kernel(
    const _Float16* __restrict__ Qh2, const _Float16* __restrict__ Kh2,
    const _Float16* __restrict__ Vt2, const float* __restrict__ CS,
    float* __restrict__ out)
{
    __shared__ _Float16 Pt[2][64*128];  // 2 x 16 KB
    const int bid = blockIdx.x;
    const int b  = bid & 7;             // b-major -> one batch per XCD
    const int qi = (bid >> 3) & 31;
    const int dh = bid >> 8;            // 0..1 d-half
    const int q0 = qi * 64;
    const int tid = threadIdx.x, lane = tid & 63, w = tid >> 6;   // w 0..3
    const int l15 = lane & 15, l4 = lane >> 4;
    const int soff = w*16 + l4*4;       // s offset within a 64-s tile

    // P-tile offsets ([64 q][128 s], 256B rows, granule-XOR low 3 bits)
    // write (8B): s = shalf*64 + w*16 + l4*4 .. +4 of row q
    const int pw0 = l15*256 + (((w*2 + (l4 >> 1)) ^ (l15 & 7)) << 4) + ((l4 & 1) << 3);
    const int pw1 = pw0 + 128;
    // read (16B, PV A-frag, K-step j): granule j*4+l4, XOR low 3 bits
    int pa[4];
    #pragma unroll
    for (int j = 0; j < 4; ++j)
        pa[j] = l15*256 + (((j >> 1)*8 + (((j & 1)*4 + l4) ^ (l15 & 7))) << 4);

    // Q fragments (held whole kernel)
    const size_t qgb = (size_t)b*128 + qi*4;
    half8 qb[4][2];
    #pragma unroll
    for (int qt = 0; qt < 4; ++qt)
        #pragma unroll
        for (int ks = 0; ks < 2; ++ks)
            qb[qt][ks] = *(const half8*)(Qh2 + (((qgb + qt)*2 + ks)*64 + lane)*8);

    // streams (bumped pointers)
    const char* Kp  = (const char*)Kh2 + (size_t)(b*128 + w)*2048 + lane*16;
    const char* Vp0 = (const char*)Vt2 + (size_t)(b*2048 + dh*16 + w*4)*1024 + lane*16;
    const char* Vp1 = Vp0 + 32768;
    const float* Cp = CS + b*Sn + soff;

    // prologue: K(0),K(1), CS(0),CS(1), V(0)
    half8 kaA[4], kaB[4], vbA[8], vbB[8];
    float4 csA0, csA1, csB0, csB1;
    kaA[0] = *(const half8*)(Kp);
    kaA[1] = *(const half8*)(Kp + 1024);
    kaA[2] = *(const half8*)(Kp + 8192);
    kaA[3] = *(const half8*)(Kp + 8192 + 1024);
    Kp += 16384;
    csA0 = *(const float4*)Cp;
    csA1 = *(const float4*)(Cp + 64);
    Cp += 128;
    #pragma unroll
    for (int d_ = 0; d_ < 4; ++d_){
        vbA[d_]   = *(const half8*)(Vp0 + d_*1024);
        vbA[4+d_] = *(const half8*)(Vp1 + d_*1024);
    }
    Vp0 += 65536; Vp1 += 65536;

    f32x4 acc[4][4];
    #pragma unroll
    for (int i = 0; i < 4; ++i)
        #pragma unroll
        for (int j = 0; j < 4; ++j){ f32x4 zz4 = {0.f,0.f,0.f,0.f}; acc[i][j] = zz4; }

    for (int it = 0; it < 8; ++it){
        SSTEP(Pt[0], kaA, kaB, csA0, csA1, csB0, csB1, vbA, vbB);
        SSTEP(Pt[1], kaB, kaA, csB0, csB1, csA0, csA1, vbB, vbA);
    }
    // (final superstep prefetches past the end; overruns land in allocated ws)

    float* ob = out + (size_t)(b*Sn + q0)*Dn + dh*256 + w*64;
    #pragma unroll
    for (int qt = 0; qt < 4; ++qt){
        const int q = qt*16 + l4*4;
        #pragma unroll
        for (int d_ = 0; d_ < 4; ++d_){
            #pragma unroll
            for (int r = 0; r < 4; ++r)
                ob[(size_t)(q + r)*Dn + d_*16 + l15] = acc[qt][d_][r];
        }
    }
}

extern "C" void kernel_launch(void* const* d_in, const int* in_sizes, int n_in,
                              void* d_out, int out_size, void* d_ws, size_t ws_size,
                              hipStream_t stream)
{
    const float* X  = (const float*)d_in[0];
    const float* Wk = (const float*)d_in[1];
    const float* bk = (const float*)d_in[2];
    const float* Wq = (const float*)d_in[3];
    const float* bq = (const float*)d_in[4];
    float* out = (float*)d_out;

    char* ws = (char*)d_ws;
    _Float16* Qh2  = (_Float16*)ws;                                  // 2 MB
    _Float16* Kh2  = (_Float16*)(ws + ((size_t)2 << 20));            // 2 MB
    _Float16* Vt2  = (_Float16*)(ws + ((size_t)4 << 20));            // 16 MB
    float*    CS   = (float*)(ws + ((size_t)20 << 20));              // 64 KB (+64 KB guard)
    _Float16* Wt16 = (_Float16*)(ws + ((size_t)20 << 20) + (2 << 16)); // 128 KB

    wtrans_kernel<<<dim3(128), dim3(256), 0, stream>>>(Wk, Wq, Wt16);
    prep_kernel<<<dim3(Bn*(Sn/32)), dim3(256), 0, stream>>>(X, Wt16, bk, bq, Qh2, Kh2, Vt2);
    stats_kernel<<<dim3(Bn*(Sn/64)), dim3(512), 0, stream>>>(Qh2, Kh2, CS);
    attn_kernel<<<dim3(Bn*(Sn/64)*2), dim3(256), 0, stream>>>(Qh2, Kh2, Vt2, CS, out);
}